// Round 1
// baseline (219.716 us; speedup 1.0000x reference)
//
#include <hip/hip_runtime.h>
#include <hip/hip_bf16.h>
#include <cstdint>
#include <cmath>

// MultiHeadAttention_38946763440365 : B=4 S=2048 D=1024 H=16 DQ=DV=64
// Pipeline: LN -> (QKV gemm, bf16 mfma) -> flash attention (len-masked) -> out gemm (+bias+residual)
// Workspace map (bytes):
//   [0,16M)    ln    bf16 [8192][1024]   (also the residual)
//   [16M,64M)  qkv   bf16 [8192][3072]   (Q | K | V)
//   [64M,80M)  vt    bf16 [64][64][2048] (V transposed per (b,h): [dv][s])
//   [80M,96M)  ctx   bf16 [8192][1024]
//   [96M,102M) wt    bf16 [3072][1024]   (Wq^T | Wkv^T)
//   [102M,104M)wot   bf16 [1024][1024]   (Wo^T)

#define DEV static __device__ __forceinline__

typedef float  f32x4 __attribute__((ext_vector_type(4)));
typedef short  s16x8 __attribute__((ext_vector_type(8)));
typedef short  s16x4 __attribute__((ext_vector_type(4)));
typedef __bf16 bf16x8 __attribute__((ext_vector_type(8)));

DEV void gload_lds16(const void* g, void* l) {
  __builtin_amdgcn_global_load_lds(
      (const __attribute__((address_space(1))) unsigned int*)g,
      (__attribute__((address_space(3))) unsigned int*)l, 16, 0, 0);
}

DEV bf16x8 ldsv(const void* p) {
  return __builtin_bit_cast(bf16x8, *(const s16x8*)p);
}

DEV f32x4 mfma16(bf16x8 a, bf16x8 b, f32x4 c) {
  return __builtin_amdgcn_mfma_f32_16x16x32_bf16(a, b, c, 0, 0, 0);
}

DEV unsigned short f2b(float f) {
  __hip_bfloat16 h = __float2bfloat16(f);
  return __builtin_bit_cast(unsigned short, h);
}

// ---------------------------------------------------------------- LayerNorm
__global__ __launch_bounds__(256) void ln_kernel(
    const float* __restrict__ x, const float* __restrict__ gamma,
    const float* __restrict__ beta, __hip_bfloat16* __restrict__ out)
{
  const int row = blockIdx.x, t = threadIdx.x;
  const float4 v = ((const float4*)(x + (size_t)row * 1024))[t];
  float s = v.x + v.y + v.z + v.w;
  float q = v.x * v.x + v.y * v.y + v.z * v.z + v.w * v.w;
#pragma unroll
  for (int m = 1; m < 64; m <<= 1) { s += __shfl_xor(s, m, 64); q += __shfl_xor(q, m, 64); }
  __shared__ float red[8];
  if ((t & 63) == 0) { red[t >> 6] = s; red[4 + (t >> 6)] = q; }
  __syncthreads();
  s = red[0] + red[1] + red[2] + red[3];
  q = red[4] + red[5] + red[6] + red[7];
  const float mu = s * (1.f / 1024.f);
  const float var = q * (1.f / 1024.f) - mu * mu;
  const float rs = rsqrtf(var + 1e-3f);
  const float4 g = ((const float4*)gamma)[t];
  const float4 bt = ((const float4*)beta)[t];
  s16x4 o;
  o[0] = (short)f2b((v.x - mu) * rs * g.x + bt.x);
  o[1] = (short)f2b((v.y - mu) * rs * g.y + bt.y);
  o[2] = (short)f2b((v.z - mu) * rs * g.z + bt.z);
  o[3] = (short)f2b((v.w - mu) * rs * g.w + bt.w);
  *(s16x4*)((short*)out + (size_t)row * 1024 + t * 4) = o;
}

// ------------------------------------------- weight convert + transpose (K=1024)
// W (Kdim x N) f32 row-major -> Wt (N x 1024) bf16, Wt[n][k] = W[k][n]
__global__ __launch_bounds__(256) void wconv(
    const float* __restrict__ W, int N, __hip_bfloat16* __restrict__ Wt)
{
  __shared__ float tile[64][65];
  const int t = threadIdx.x;
  const int k0 = blockIdx.x * 64, n0 = blockIdx.y * 64;
#pragma unroll
  for (int p = 0; p < 4; ++p) {
    int r = p * 16 + (t >> 4), c4 = (t & 15) * 4;
    float4 v = *(const float4*)(W + (size_t)(k0 + r) * N + n0 + c4);
    tile[r][c4] = v.x; tile[r][c4 + 1] = v.y; tile[r][c4 + 2] = v.z; tile[r][c4 + 3] = v.w;
  }
  __syncthreads();
#pragma unroll
  for (int p = 0; p < 4; ++p) {
    int n = p * 16 + (t >> 4), kc = (t & 15) * 4;
    s16x4 o;
    o[0] = (short)f2b(tile[kc][n]);     o[1] = (short)f2b(tile[kc + 1][n]);
    o[2] = (short)f2b(tile[kc + 2][n]); o[3] = (short)f2b(tile[kc + 3][n]);
    *(s16x4*)((short*)Wt + (size_t)(n0 + n) * 1024 + k0 + kc) = o;
  }
}

// ------------------------------------------------------- GEMM: C = A @ Bt^T
// A [M][1024] bf16, Bt [N][1024] bf16 (pre-transposed).  128x128 tile, BK=64,
// 4 waves (2x2), global_load_lds w=16, XOR chunk-swizzle (c ^= row&7).
template<bool RESID>
__global__ __launch_bounds__(256, 2) void gemm_bt(
    const __hip_bfloat16* __restrict__ A, const __hip_bfloat16* __restrict__ Bt,
    const float* __restrict__ bias0, const float* __restrict__ bias1, int split,
    const __hip_bfloat16* __restrict__ resid,
    __hip_bfloat16* __restrict__ outb, float* __restrict__ outf, int Ncols)
{
  __shared__ __align__(16) short sA[128 * 64];
  __shared__ __align__(16) short sB[128 * 64];
  const int t = threadIdx.x, l = t & 63, w = t >> 6;
  const int wr = w >> 1, wc = w & 1, lr = l & 15, lg = l >> 4;
  const int row0 = blockIdx.y * 128, col0 = blockIdx.x * 128;
  f32x4 acc[4][4] = {};

  for (int kt = 0; kt < 1024; kt += 64) {
#pragma unroll
    for (int p = 0; p < 4; ++p) {
      const int L = p * 4096 + t * 16;
      const int r = L >> 7, c = ((L >> 4) & 7) ^ (r & 7);
      gload_lds16((const char*)A + ((size_t)(row0 + r) * 1024 + kt + c * 8) * 2, (char*)sA + L);
    }
#pragma unroll
    for (int p = 0; p < 4; ++p) {
      const int L = p * 4096 + t * 16;
      const int r = L >> 7, c = ((L >> 4) & 7) ^ (r & 7);
      gload_lds16((const char*)Bt + ((size_t)(col0 + r) * 1024 + kt + c * 8) * 2, (char*)sB + L);
    }
    __syncthreads();

    bf16x8 af[4][2], bfr[4][2];
#pragma unroll
    for (int mb = 0; mb < 4; ++mb) {
      const int ar = wr * 64 + mb * 16 + lr;
#pragma unroll
      for (int kk = 0; kk < 2; ++kk)
        af[mb][kk] = ldsv((const char*)sA + ar * 128 + (((kk * 4 + lg) ^ (ar & 7)) * 16));
    }
#pragma unroll
    for (int nb = 0; nb < 4; ++nb) {
      const int br = wc * 64 + nb * 16 + lr;
#pragma unroll
      for (int kk = 0; kk < 2; ++kk)
        bfr[nb][kk] = ldsv((const char*)sB + br * 128 + (((kk * 4 + lg) ^ (br & 7)) * 16));
    }
#pragma unroll
    for (int kk = 0; kk < 2; ++kk)
#pragma unroll
      for (int mb = 0; mb < 4; ++mb)
#pragma unroll
        for (int nb = 0; nb < 4; ++nb)
          acc[mb][nb] = mfma16(af[mb][kk], bfr[nb][kk], acc[mb][nb]);
    __syncthreads();
  }

#pragma unroll
  for (int mb = 0; mb < 4; ++mb) {
    const int rbase = row0 + wr * 64 + mb * 16 + lg * 4;
#pragma unroll
    for (int nb = 0; nb < 4; ++nb) {
      const int col = col0 + wc * 64 + nb * 16 + lr;
      const float bias = (col < split) ? bias0[col] : bias1[col - split];
#pragma unroll
      for (int jr = 0; jr < 4; ++jr) {
        const size_t idx = (size_t)(rbase + jr) * Ncols + col;
        float v = acc[mb][nb][jr] + bias;
        if (RESID) outf[idx] = v + __bfloat162float(resid[idx]);
        else       outb[idx] = __float2bfloat16(v);
      }
    }
  }
}

// --------------------------------------- V transpose: qkv V-part -> [bh][dv][s]
__global__ __launch_bounds__(256) void vtrans(
    const __hip_bfloat16* __restrict__ qkv, __hip_bfloat16* __restrict__ vt)
{
  __shared__ __align__(16) short tile[64][72];
  const int t = threadIdx.x;
  const int s0 = blockIdx.x * 64;
  const int bh = blockIdx.y, b = bh >> 4, h = bh & 15;
#pragma unroll
  for (int p = 0; p < 2; ++p) {
    int idx = p * 256 + t;
    int r = idx >> 3, c = idx & 7;
    s16x8 vv = *(const s16x8*)((const short*)qkv +
        (size_t)(b * 2048 + s0 + r) * 3072 + 2048 + h * 64 + c * 8);
    *(s16x8*)((char*)tile + r * 144 + c * 16) = vv;
  }
  __syncthreads();
  const int dv = t >> 2, sc = (t & 3) * 16;
  s16x8 a, bvec;
#pragma unroll
  for (int e = 0; e < 8; ++e) a[e] = tile[sc + e][dv];
#pragma unroll
  for (int e = 0; e < 8; ++e) bvec[e] = tile[sc + 8 + e][dv];
  short* dst = (short*)vt + (size_t)(bh * 64 + dv) * 2048 + s0 + sc;
  *(s16x8*)dst = a;
  *(s16x8*)(dst + 8) = bvec;
}

// ----------------------------------------------------------- flash attention
// grid (S/128, B*H); 4 waves x 32 q-rows; KVBLK=64; online softmax.
__global__ __launch_bounds__(256, 2) void attn_kernel(
    const __hip_bfloat16* __restrict__ qkv, const __hip_bfloat16* __restrict__ vt,
    const int* __restrict__ lens, __hip_bfloat16* __restrict__ ctx)
{
  __shared__ __align__(16) short sK[64 * 64];
  __shared__ __align__(16) short sV[64 * 64];
  __shared__ __align__(16) short sP[4][32 * 72];
  const int t = threadIdx.x, l = t & 63, w = t >> 6;
  const int lr = l & 15, lg = l >> 4;
  const int bh = blockIdx.y, b = bh >> 4, h = bh & 15;
  const int q0 = blockIdx.x * 128 + w * 32;
  const int len = lens[b];
  const float NEG = -__builtin_inff();

  bf16x8 qf[2][2];
#pragma unroll
  for (int mb = 0; mb < 2; ++mb)
#pragma unroll
    for (int kk = 0; kk < 2; ++kk)
      qf[mb][kk] = ldsv((const char*)qkv +
          ((size_t)(b * 2048 + q0 + mb * 16 + lr) * 3072 + h * 64 + kk * 32 + lg * 8) * 2);

  f32x4 o[2][4] = {};
  float mrun[2][4], lrun[2][4];
#pragma unroll
  for (int mb = 0; mb < 2; ++mb)
#pragma unroll
    for (int jr = 0; jr < 4; ++jr) { mrun[mb][jr] = NEG; lrun[mb][jr] = 0.f; }

  const int nt = (len + 63) >> 6;
  for (int ti = 0; ti < nt; ++ti) {
    const int kv0 = ti * 64;
#pragma unroll
    for (int p = 0; p < 2; ++p) {
      const int L = p * 4096 + t * 16;
      const int r = L >> 7, c = ((L >> 4) & 7) ^ (r & 7);
      gload_lds16((const char*)qkv +
          ((size_t)(b * 2048 + kv0 + r) * 3072 + 1024 + h * 64 + c * 8) * 2, (char*)sK + L);
    }
#pragma unroll
    for (int p = 0; p < 2; ++p) {
      const int L = p * 4096 + t * 16;
      const int r = L >> 7, c = ((L >> 4) & 7) ^ (r & 7);
      gload_lds16((const char*)vt +
          ((size_t)(bh * 64 + r) * 2048 + kv0 + c * 8) * 2, (char*)sV + L);
    }
    __syncthreads();

    f32x4 sf[2][4] = {};
#pragma unroll
    for (int kk = 0; kk < 2; ++kk) {
      bf16x8 bk[4];
#pragma unroll
      for (int nb = 0; nb < 4; ++nb) {
        const int br = nb * 16 + lr;
        bk[nb] = ldsv((const char*)sK + br * 128 + (((kk * 4 + lg) ^ (br & 7)) * 16));
      }
#pragma unroll
      for (int mb = 0; mb < 2; ++mb)
#pragma unroll
        for (int nb = 0; nb < 4; ++nb)
          sf[mb][nb] = mfma16(qf[mb][kk], bk[nb], sf[mb][nb]);
    }
#pragma unroll
    for (int mb = 0; mb < 2; ++mb)
#pragma unroll
      for (int nb = 0; nb < 4; ++nb)
        sf[mb][nb] *= 0.125f;
    if (kv0 + 64 > len) {
#pragma unroll
      for (int nb = 0; nb < 4; ++nb)
        if (kv0 + nb * 16 + lr >= len) {
#pragma unroll
          for (int mb = 0; mb < 2; ++mb)
#pragma unroll
            for (int jr = 0; jr < 4; ++jr)
              sf[mb][nb][jr] = NEG;
        }
    }
#pragma unroll
    for (int mb = 0; mb < 2; ++mb) {
      float corr[4];
#pragma unroll
      for (int jr = 0; jr < 4; ++jr) {
        float rm = fmaxf(fmaxf(sf[mb][0][jr], sf[mb][1][jr]),
                         fmaxf(sf[mb][2][jr], sf[mb][3][jr]));
        rm = fmaxf(rm, __shfl_xor(rm, 1, 64));
        rm = fmaxf(rm, __shfl_xor(rm, 2, 64));
        rm = fmaxf(rm, __shfl_xor(rm, 4, 64));
        rm = fmaxf(rm, __shfl_xor(rm, 8, 64));
        const float mnew = fmaxf(mrun[mb][jr], rm);
        corr[jr] = __expf(mrun[mb][jr] - mnew);
        mrun[mb][jr] = mnew;
      }
#pragma unroll
      for (int nb = 0; nb < 4; ++nb)
#pragma unroll
        for (int jr = 0; jr < 4; ++jr)
          sf[mb][nb][jr] = __expf(sf[mb][nb][jr] - mrun[mb][jr]);
#pragma unroll
      for (int jr = 0; jr < 4; ++jr) {
        float rs = sf[mb][0][jr] + sf[mb][1][jr] + sf[mb][2][jr] + sf[mb][3][jr];
        rs += __shfl_xor(rs, 1, 64);
        rs += __shfl_xor(rs, 2, 64);
        rs += __shfl_xor(rs, 4, 64);
        rs += __shfl_xor(rs, 8, 64);
        lrun[mb][jr] = lrun[mb][jr] * corr[jr] + rs;
      }
#pragma unroll
      for (int nb = 0; nb < 4; ++nb)
#pragma unroll
        for (int jr = 0; jr < 4; ++jr)
          o[mb][nb][jr] *= corr[jr];
#pragma unroll
      for (int nb = 0; nb < 4; ++nb)
#pragma unroll
        for (int jr = 0; jr < 4; ++jr)
          sP[w][(mb * 16 + lg * 4 + jr) * 72 + nb * 16 + lr] = (short)f2b(sf[mb][nb][jr]);
    }
    __syncthreads();  // P visible (also keeps waves phase-aligned)
#pragma unroll
    for (int kk = 0; kk < 2; ++kk) {
      bf16x8 pa[2], vf[4];
#pragma unroll
      for (int mb = 0; mb < 2; ++mb)
        pa[mb] = ldsv((const char*)&sP[w][0] + (mb * 16 + lr) * 144 + kk * 64 + lg * 16);
#pragma unroll
      for (int nb = 0; nb < 4; ++nb) {
        const int vr = nb * 16 + lr;
        vf[nb] = ldsv((const char*)sV + vr * 128 + (((kk * 4 + lg) ^ (vr & 7)) * 16));
      }
#pragma unroll
      for (int mb = 0; mb < 2; ++mb)
#pragma unroll
        for (int nb = 0; nb < 4; ++nb)
          o[mb][nb] = mfma16(pa[mb], vf[nb], o[mb][nb]);
    }
    __syncthreads();
  }

#pragma unroll
  for (int mb = 0; mb < 2; ++mb) {
#pragma unroll
    for (int jr = 0; jr < 4; ++jr) {
      const float inv = 1.f / lrun[mb][jr];
      const int r = q0 + mb * 16 + lg * 4 + jr;
#pragma unroll
      for (int nb = 0; nb < 4; ++nb)
        ctx[(size_t)(b * 2048 + r) * 1024 + h * 64 + nb * 16 + lr] =
            __float2bfloat16(o[mb][nb][jr] * inv);
    }
  }
}

// ------------------------------------------------------------------- launch
extern "C" void kernel_launch(void* const* d_in, const int* in_sizes, int n_in,
                              void* d_out, int out_size, void* d_ws, size_t ws_size,
                              hipStream_t stream)
{
  const float* x     = (const float*)d_in[0];
  const int*   lens  = (const int*)d_in[2];
  const float* Wq    = (const float*)d_in[3];
  const float* bq    = (const float*)d_in[4];
  const float* Wkv   = (const float*)d_in[5];
  const float* bkv   = (const float*)d_in[6];
  const float* Wo    = (const float*)d_in[7];
  const float* bo    = (const float*)d_in[8];
  const float* gamma = (const float*)d_in[9];
  const float* beta  = (const float*)d_in[10];
  float* out = (float*)d_out;

  char* ws = (char*)d_ws;
  __hip_bfloat16* ln  = (__hip_bfloat16*)(ws);
  __hip_bfloat16* qkv = (__hip_bfloat16*)(ws + ((size_t)16 << 20));
  __hip_bfloat16* vt  = (__hip_bfloat16*)(ws + ((size_t)64 << 20));
  __hip_bfloat16* ctx = (__hip_bfloat16*)(ws + ((size_t)80 << 20));
  __hip_bfloat16* wt  = (__hip_bfloat16*)(ws + ((size_t)96 << 20));
  __hip_bfloat16* wot = (__hip_bfloat16*)(ws + ((size_t)102 << 20));

  ln_kernel<<<dim3(8192), dim3(256), 0, stream>>>(x, gamma, beta, ln);
  wconv<<<dim3(16, 16), dim3(256), 0, stream>>>(Wq, 1024, wt);
  wconv<<<dim3(16, 32), dim3(256), 0, stream>>>(Wkv, 2048, wt + (size_t)1024 * 1024);
  wconv<<<dim3(16, 16), dim3(256), 0, stream>>>(Wo, 1024, wot);
  gemm_bt<false><<<dim3(24, 64), dim3(256), 0, stream>>>(
      ln, wt, bq, bkv, 1024, (const __hip_bfloat16*)nullptr,
      qkv, (float*)nullptr, 3072);
  vtrans<<<dim3(32, 64), dim3(256), 0, stream>>>(qkv, vt);
  attn_kernel<<<dim3(16, 64), dim3(256), 0, stream>>>(qkv, vt, lens, ctx);
  gemm_bt<true><<<dim3(8, 64), dim3(256), 0, stream>>>(
      ctx, wot, bo, bo, 1 << 30, ln,
      (__hip_bfloat16*)nullptr, out, 1024);
}

// Round 2
// 194.751 us; speedup vs baseline: 1.1282x; 1.1282x over previous
//
#include <hip/hip_runtime.h>
#include <hip/hip_bf16.h>
#include <cstdint>
#include <cmath>

// MultiHeadAttention_38946763440365 : B=4 S=2048 D=1024 H=16 DQ=DV=64
// Pipeline: LN -> (QKV gemm, bf16 mfma) -> flash attention (len-masked) -> out gemm (+bias+residual)
// Workspace map (bytes):
//   [0,16M)    ln    bf16 [8192][1024]   (also the residual)
//   [16M,64M)  qkv   bf16 [8192][3072]   (Q | K | V)
//   [64M,80M)  vt    bf16 [64][64][2048] (V transposed per (b,h): [dv][s])
//   [80M,96M)  ctx   bf16 [8192][1024]
//   [96M,102M) wt    bf16 [3072][1024]   (Wq^T | Wkv^T)
//   [102M,104M)wot   bf16 [1024][1024]   (Wo^T)

#define DEV static __device__ __forceinline__

typedef float  f32x4 __attribute__((ext_vector_type(4)));
typedef short  s16x8 __attribute__((ext_vector_type(8)));
typedef short  s16x4 __attribute__((ext_vector_type(4)));
typedef __bf16 bf16x8 __attribute__((ext_vector_type(8)));

DEV void gload_lds16(const void* g, void* l) {
  __builtin_amdgcn_global_load_lds(
      (const __attribute__((address_space(1))) unsigned int*)g,
      (__attribute__((address_space(3))) unsigned int*)l, 16, 0, 0);
}

DEV bf16x8 ldsv(const void* p) {
  return __builtin_bit_cast(bf16x8, *(const s16x8*)p);
}

DEV f32x4 mfma16(bf16x8 a, bf16x8 b, f32x4 c) {
  return __builtin_amdgcn_mfma_f32_16x16x32_bf16(a, b, c, 0, 0, 0);
}

DEV unsigned short f2b(float f) {
  __hip_bfloat16 h = __float2bfloat16(f);
  return __builtin_bit_cast(unsigned short, h);
}

// ---------------------------------------------------------------- LayerNorm
__global__ __launch_bounds__(256) void ln_kernel(
    const float* __restrict__ x, const float* __restrict__ gamma,
    const float* __restrict__ beta, __hip_bfloat16* __restrict__ out)
{
  const int row = blockIdx.x, t = threadIdx.x;
  const float4 v = ((const float4*)(x + (size_t)row * 1024))[t];
  float s = v.x + v.y + v.z + v.w;
  float q = v.x * v.x + v.y * v.y + v.z * v.z + v.w * v.w;
#pragma unroll
  for (int m = 1; m < 64; m <<= 1) { s += __shfl_xor(s, m, 64); q += __shfl_xor(q, m, 64); }
  __shared__ float red[8];
  if ((t & 63) == 0) { red[t >> 6] = s; red[4 + (t >> 6)] = q; }
  __syncthreads();
  s = red[0] + red[1] + red[2] + red[3];
  q = red[4] + red[5] + red[6] + red[7];
  const float mu = s * (1.f / 1024.f);
  const float var = q * (1.f / 1024.f) - mu * mu;
  const float rs = rsqrtf(var + 1e-3f);
  const float4 g = ((const float4*)gamma)[t];
  const float4 bt = ((const float4*)beta)[t];
  s16x4 o;
  o[0] = (short)f2b((v.x - mu) * rs * g.x + bt.x);
  o[1] = (short)f2b((v.y - mu) * rs * g.y + bt.y);
  o[2] = (short)f2b((v.z - mu) * rs * g.z + bt.z);
  o[3] = (short)f2b((v.w - mu) * rs * g.w + bt.w);
  *(s16x4*)((short*)out + (size_t)row * 1024 + t * 4) = o;
}

// ------------------------------------------- weight convert + transpose (K=1024)
__global__ __launch_bounds__(256) void wconv(
    const float* __restrict__ W, int N, __hip_bfloat16* __restrict__ Wt)
{
  __shared__ float tile[64][65];
  const int t = threadIdx.x;
  const int k0 = blockIdx.x * 64, n0 = blockIdx.y * 64;
#pragma unroll
  for (int p = 0; p < 4; ++p) {
    int r = p * 16 + (t >> 4), c4 = (t & 15) * 4;
    float4 v = *(const float4*)(W + (size_t)(k0 + r) * N + n0 + c4);
    tile[r][c4] = v.x; tile[r][c4 + 1] = v.y; tile[r][c4 + 2] = v.z; tile[r][c4 + 3] = v.w;
  }
  __syncthreads();
#pragma unroll
  for (int p = 0; p < 4; ++p) {
    int n = p * 16 + (t >> 4), kc = (t & 15) * 4;
    s16x4 o;
    o[0] = (short)f2b(tile[kc][n]);     o[1] = (short)f2b(tile[kc + 1][n]);
    o[2] = (short)f2b(tile[kc + 2][n]); o[3] = (short)f2b(tile[kc + 3][n]);
    *(s16x4*)((short*)Wt + (size_t)(n0 + n) * 1024 + k0 + kc) = o;
  }
}

// ------------------------------------------------------- GEMM: C = A @ Bt^T
template<bool RESID>
__global__ __launch_bounds__(256, 2) void gemm_bt(
    const __hip_bfloat16* __restrict__ A, const __hip_bfloat16* __restrict__ Bt,
    const float* __restrict__ bias0, const float* __restrict__ bias1, int split,
    const __hip_bfloat16* __restrict__ resid,
    __hip_bfloat16* __restrict__ outb, float* __restrict__ outf, int Ncols)
{
  __shared__ __align__(16) short sA[128 * 64];
  __shared__ __align__(16) short sB[128 * 64];
  const int t = threadIdx.x, l = t & 63, w = t >> 6;
  const int wr = w >> 1, wc = w & 1, lr = l & 15, lg = l >> 4;
  const int row0 = blockIdx.y * 128, col0 = blockIdx.x * 128;
  f32x4 acc[4][4] = {};

  for (int kt = 0; kt < 1024; kt += 64) {
#pragma unroll
    for (int p = 0; p < 4; ++p) {
      const int L = p * 4096 + t * 16;
      const int r = L >> 7, c = ((L >> 4) & 7) ^ (r & 7);
      gload_lds16((const char*)A + ((size_t)(row0 + r) * 1024 + kt + c * 8) * 2, (char*)sA + L);
    }
#pragma unroll
    for (int p = 0; p < 4; ++p) {
      const int L = p * 4096 + t * 16;
      const int r = L >> 7, c = ((L >> 4) & 7) ^ (r & 7);
      gload_lds16((const char*)Bt + ((size_t)(col0 + r) * 1024 + kt + c * 8) * 2, (char*)sB + L);
    }
    __syncthreads();

    bf16x8 af[4][2], bfr[4][2];
#pragma unroll
    for (int mb = 0; mb < 4; ++mb) {
      const int ar = wr * 64 + mb * 16 + lr;
#pragma unroll
      for (int kk = 0; kk < 2; ++kk)
        af[mb][kk] = ldsv((const char*)sA + ar * 128 + (((kk * 4 + lg) ^ (ar & 7)) * 16));
    }
#pragma unroll
    for (int nb = 0; nb < 4; ++nb) {
      const int br = wc * 64 + nb * 16 + lr;
#pragma unroll
      for (int kk = 0; kk < 2; ++kk)
        bfr[nb][kk] = ldsv((const char*)sB + br * 128 + (((kk * 4 + lg) ^ (br & 7)) * 16));
    }
#pragma unroll
    for (int kk = 0; kk < 2; ++kk)
#pragma unroll
      for (int mb = 0; mb < 4; ++mb)
#pragma unroll
        for (int nb = 0; nb < 4; ++nb)
          acc[mb][nb] = mfma16(af[mb][kk], bfr[nb][kk], acc[mb][nb]);
    __syncthreads();
  }

#pragma unroll
  for (int mb = 0; mb < 4; ++mb) {
    const int rbase = row0 + wr * 64 + mb * 16 + lg * 4;
#pragma unroll
    for (int nb = 0; nb < 4; ++nb) {
      const int col = col0 + wc * 64 + nb * 16 + lr;
      const float bias = (col < split) ? bias0[col] : bias1[col - split];
#pragma unroll
      for (int jr = 0; jr < 4; ++jr) {
        const size_t idx = (size_t)(rbase + jr) * Ncols + col;
        float v = acc[mb][nb][jr] + bias;
        if (RESID) outf[idx] = v + __bfloat162float(resid[idx]);
        else       outb[idx] = __float2bfloat16(v);
      }
    }
  }
}

// --------------------------------------- V transpose: qkv V-part -> [bh][dv][s]
__global__ __launch_bounds__(256) void vtrans(
    const __hip_bfloat16* __restrict__ qkv, __hip_bfloat16* __restrict__ vt)
{
  __shared__ __align__(16) short tile[64][72];
  const int t = threadIdx.x;
  const int s0 = blockIdx.x * 64;
  const int bh = blockIdx.y, b = bh >> 4, h = bh & 15;
#pragma unroll
  for (int p = 0; p < 2; ++p) {
    int idx = p * 256 + t;
    int r = idx >> 3, c = idx & 7;
    s16x8 vv = *(const s16x8*)((const short*)qkv +
        (size_t)(b * 2048 + s0 + r) * 3072 + 2048 + h * 64 + c * 8);
    *(s16x8*)((char*)tile + r * 144 + c * 16) = vv;
  }
  __syncthreads();
  const int dv = t >> 2, sc = (t & 3) * 16;
  s16x8 a, bvec;
#pragma unroll
  for (int e = 0; e < 8; ++e) a[e] = tile[sc + e][dv];
#pragma unroll
  for (int e = 0; e < 8; ++e) bvec[e] = tile[sc + 8 + e][dv];
  short* dst = (short*)vt + (size_t)(bh * 64 + dv) * 2048 + s0 + sc;
  *(s16x8*)dst = a;
  *(s16x8*)(dst + 8) = bvec;
}

// ----------------------------------------------------------- flash attention
// grid (S/128, B*H); 4 waves x 32 q-rows; KVBLK=64; online softmax (log2 domain).
// Double-buffered K/V staging with counted vmcnt (T3/T4); denominator via
// ones-column MFMA; defer-rescale (T13, THR=3 in log2 units).
__global__ __launch_bounds__(256, 3) void attn_kernel(
    const __hip_bfloat16* __restrict__ qkv, const __hip_bfloat16* __restrict__ vt,
    const int* __restrict__ lens, __hip_bfloat16* __restrict__ ctx)
{
  __shared__ __align__(16) short sK[2][64 * 64];
  __shared__ __align__(16) short sV[2][64 * 64];
  __shared__ __align__(16) short sP[4][32 * 72];
  const int t = threadIdx.x, l = t & 63, w = t >> 6;
  const int lr = l & 15, lg = l >> 4;
  const int bh = blockIdx.y, b = bh >> 4, h = bh & 15;
  const int q0 = blockIdx.x * 128 + w * 32;
  const int len = lens[b];
  const float NEG = -__builtin_inff();
  const float QSC = 0.18033688f;  // 0.125 * log2(e) -> softmax in log2 domain

  // Q fragments, scale folded in
  bf16x8 qf[2][2];
#pragma unroll
  for (int mb = 0; mb < 2; ++mb)
#pragma unroll
    for (int kk = 0; kk < 2; ++kk) {
      bf16x8 r = ldsv((const char*)qkv +
          ((size_t)(b * 2048 + q0 + mb * 16 + lr) * 3072 + h * 64 + kk * 32 + lg * 8) * 2);
#pragma unroll
      for (int e = 0; e < 8; ++e) qf[mb][kk][e] = (__bf16)((float)r[e] * QSC);
    }

  bf16x8 vones;
#pragma unroll
  for (int e = 0; e < 8; ++e) vones[e] = (__bf16)1.0f;

  f32x4 o[2][5] = {};   // [][4] accumulates the softmax denominator
  float mrun[2][4];
#pragma unroll
  for (int mb = 0; mb < 2; ++mb)
#pragma unroll
    for (int jr = 0; jr < 4; ++jr) mrun[mb][jr] = NEG;

  auto stage = [&](short* dK, short* dV, int kv0) {
#pragma unroll
    for (int p = 0; p < 2; ++p) {
      const int L = p * 4096 + t * 16;
      const int r = L >> 7, c = ((L >> 4) & 7) ^ (r & 7);
      gload_lds16((const char*)qkv +
          ((size_t)(b * 2048 + kv0 + r) * 3072 + 1024 + h * 64 + c * 8) * 2, (char*)dK + L);
    }
#pragma unroll
    for (int p = 0; p < 2; ++p) {
      const int L = p * 4096 + t * 16;
      const int r = L >> 7, c = ((L >> 4) & 7) ^ (r & 7);
      gload_lds16((const char*)vt +
          ((size_t)(bh * 64 + r) * 2048 + kv0 + c * 8) * 2, (char*)dV + L);
    }
  };

  const int nt = (len + 63) >> 6;
  short* curK = sK[0]; short* nxtK = sK[1];
  short* curV = sV[0]; short* nxtV = sV[1];
  stage(curK, curV, 0);

  for (int ti = 0; ti < nt; ++ti) {
    const int kv0 = ti * 64;
    if (ti + 1 < nt) {
      stage(nxtK, nxtV, kv0 + 64);
      asm volatile("s_waitcnt vmcnt(4)" ::: "memory");   // prev tile's 4 loads done
    } else {
      asm volatile("s_waitcnt vmcnt(0)" ::: "memory");
    }
    __builtin_amdgcn_s_barrier();
    asm volatile("" ::: "memory");

    // ---- QK^T (log2-scaled)
    f32x4 sf[2][4] = {};
#pragma unroll
    for (int kk = 0; kk < 2; ++kk) {
      bf16x8 bk[4];
#pragma unroll
      for (int nb = 0; nb < 4; ++nb) {
        const int br = nb * 16 + lr;
        bk[nb] = ldsv((const char*)curK + br * 128 + (((kk * 4 + lg) ^ (br & 7)) * 16));
      }
#pragma unroll
      for (int mb = 0; mb < 2; ++mb)
#pragma unroll
        for (int nb = 0; nb < 4; ++nb)
          sf[mb][nb] = mfma16(qf[mb][kk], bk[nb], sf[mb][nb]);
    }

    if (kv0 + 64 > len) {
#pragma unroll
      for (int nb = 0; nb < 4; ++nb)
        if (kv0 + nb * 16 + lr >= len) {
#pragma unroll
          for (int mb = 0; mb < 2; ++mb)
#pragma unroll
            for (int jr = 0; jr < 4; ++jr)
              sf[mb][nb][jr] = NEG;
        }
    }

    // ---- online softmax, defer-rescale
#pragma unroll
    for (int mb = 0; mb < 2; ++mb) {
      float rm[4];
#pragma unroll
      for (int jr = 0; jr < 4; ++jr) {
        float m0 = fmaxf(fmaxf(sf[mb][0][jr], sf[mb][1][jr]),
                         fmaxf(sf[mb][2][jr], sf[mb][3][jr]));
        m0 = fmaxf(m0, __shfl_xor(m0, 1, 64));
        m0 = fmaxf(m0, __shfl_xor(m0, 2, 64));
        m0 = fmaxf(m0, __shfl_xor(m0, 4, 64));
        m0 = fmaxf(m0, __shfl_xor(m0, 8, 64));
        rm[jr] = m0;
      }
      const bool need = (rm[0] > mrun[mb][0] + 3.f) || (rm[1] > mrun[mb][1] + 3.f) ||
                        (rm[2] > mrun[mb][2] + 3.f) || (rm[3] > mrun[mb][3] + 3.f);
      if (__any(need)) {
#pragma unroll
        for (int jr = 0; jr < 4; ++jr) {
          const float mnew = fmaxf(mrun[mb][jr], rm[jr]);
          const float corr = __builtin_amdgcn_exp2f(mrun[mb][jr] - mnew);
          mrun[mb][jr] = mnew;
#pragma unroll
          for (int nb = 0; nb < 5; ++nb) o[mb][nb][jr] *= corr;
        }
      }
#pragma unroll
      for (int nb = 0; nb < 4; ++nb)
#pragma unroll
        for (int jr = 0; jr < 4; ++jr)
          sP[w][(mb * 16 + lg * 4 + jr) * 72 + nb * 16 + lr] =
              (short)f2b(__builtin_amdgcn_exp2f(sf[mb][nb][jr] - mrun[mb][jr]));
    }

    // ---- PV (sP is per-wave: same-wave DS ordering suffices, no barrier)
#pragma unroll
    for (int kk = 0; kk < 2; ++kk) {
      bf16x8 pa[2], vf[4];
#pragma unroll
      for (int mb = 0; mb < 2; ++mb)
        pa[mb] = ldsv((const char*)&sP[w][0] + (mb * 16 + lr) * 144 + kk * 64 + lg * 16);
#pragma unroll
      for (int nb = 0; nb < 4; ++nb) {
        const int vr = nb * 16 + lr;
        vf[nb] = ldsv((const char*)curV + vr * 128 + (((kk * 4 + lg) ^ (vr & 7)) * 16));
      }
#pragma unroll
      for (int mb = 0; mb < 2; ++mb) {
#pragma unroll
        for (int nb = 0; nb < 4; ++nb)
          o[mb][nb] = mfma16(pa[mb], vf[nb], o[mb][nb]);
        o[mb][4] = mfma16(pa[mb], vones, o[mb][4]);   // row-sum -> denominator
      }
    }

    asm volatile("s_waitcnt lgkmcnt(0)" ::: "memory");
    __builtin_amdgcn_s_barrier();    // all reads of cur done -> safe to restage
    asm volatile("" ::: "memory");
    short* tk = curK; curK = nxtK; nxtK = tk;
    short* tv = curV; curV = nxtV; nxtV = tv;
  }

#pragma unroll
  for (int mb = 0; mb < 2; ++mb) {
#pragma unroll
    for (int jr = 0; jr < 4; ++jr) {
      const float inv = 1.f / o[mb][4][jr];
      const int r = q0 + mb * 16 + lg * 4 + jr;
#pragma unroll
      for (int nb = 0; nb < 4; ++nb)
        ctx[(size_t)(b * 2048 + r) * 1024 + h * 64 + nb * 16 + lr] =
            __float2bfloat16(o[mb][nb][jr] * inv);
    }
  }
}

// ------------------------------------------------------------------- launch
extern "C" void kernel_launch(void* const* d_in, const int* in_sizes, int n_in,
                              void* d_out, int out_size, void* d_ws, size_t ws_size,
                              hipStream_t stream)
{
  const float* x     = (const float*)d_in[0];
  const int*   lens  = (const int*)d_in[2];
  const float* Wq    = (const float*)d_in[3];
  const float* bq    = (const float*)d_in[4];
  const float* Wkv   = (const float*)d_in[5];
  const float* bkv   = (const float*)d_in[6];
  const float* Wo    = (const float*)d_in[7];
  const float* bo    = (const float*)d_in[8];
  const float* gamma = (const float*)d_in[9];
  const float* beta  = (const float*)d_in[10];
  float* out = (float*)d_out;

  char* ws = (char*)d_ws;
  __hip_bfloat16* ln  = (__hip_bfloat16*)(ws);
  __hip_bfloat16* qkv = (__hip_bfloat16*)(ws + ((size_t)16 << 20));
  __hip_bfloat16* vt  = (__hip_bfloat16*)(ws + ((size_t)64 << 20));
  __hip_bfloat16* ctx = (__hip_bfloat16*)(ws + ((size_t)80 << 20));
  __hip_bfloat16* wt  = (__hip_bfloat16*)(ws + ((size_t)96 << 20));
  __hip_bfloat16* wot = (__hip_bfloat16*)(ws + ((size_t)102 << 20));

  ln_kernel<<<dim3(8192), dim3(256), 0, stream>>>(x, gamma, beta, ln);
  wconv<<<dim3(16, 16), dim3(256), 0, stream>>>(Wq, 1024, wt);
  wconv<<<dim3(16, 32), dim3(256), 0, stream>>>(Wkv, 2048, wt + (size_t)1024 * 1024);
  wconv<<<dim3(16, 16), dim3(256), 0, stream>>>(Wo, 1024, wot);
  gemm_bt<false><<<dim3(24, 64), dim3(256), 0, stream>>>(
      ln, wt, bq, bkv, 1024, (const __hip_bfloat16*)nullptr,
      qkv, (float*)nullptr, 3072);
  vtrans<<<dim3(32, 64), dim3(256), 0, stream>>>(qkv, vt);
  attn_kernel<<<dim3(16, 64), dim3(256), 0, stream>>>(qkv, vt, lens, ctx);
  gemm_bt<true><<<dim3(8, 64), dim3(256), 0, stream>>>(
      ctx, wot, bo, bo, 1 << 30, ln,
      (__hip_bfloat16*)nullptr, out, 1024);
}

// Round 3
// 174.852 us; speedup vs baseline: 1.2566x; 1.1138x over previous
//
#include <hip/hip_runtime.h>
#include <hip/hip_bf16.h>
#include <cstdint>
#include <cmath>

// MultiHeadAttention_38946763440365 : B=4 S=2048 D=1024 H=16 DQ=DV=64
// LN -> QKV gemm (bf16 mfma) -> flash attention (swapped-QK in-register softmax) -> out gemm
// Workspace map (bytes):
//   [0,16M)    ln    bf16 [8192][1024]   (also the residual)
//   [16M,64M)  qkv   bf16 [8192][3072]   (Q | K | V)
//   [64M,80M)  vt    bf16 [64][64][2048] (V transposed per (b,h): [dv][s])
//   [80M,96M)  ctx   bf16 [8192][1024]
//   [96M,102M) wt    bf16 [3072][1024]   (Wq^T | Wkv^T)
//   [102M,104M)wot   bf16 [1024][1024]   (Wo^T)

#define DEV static __device__ __forceinline__

typedef float  f32x4 __attribute__((ext_vector_type(4)));
typedef short  s16x8 __attribute__((ext_vector_type(8)));
typedef short  s16x4 __attribute__((ext_vector_type(4)));
typedef __bf16 bf16x8 __attribute__((ext_vector_type(8)));
typedef unsigned int u32x4 __attribute__((ext_vector_type(4)));

DEV void gload_lds16(const void* g, void* l) {
  __builtin_amdgcn_global_load_lds(
      (const __attribute__((address_space(1))) unsigned int*)g,
      (__attribute__((address_space(3))) unsigned int*)l, 16, 0, 0);
}

DEV bf16x8 ldsv(const void* p) {
  return __builtin_bit_cast(bf16x8, *(const s16x8*)p);
}

DEV f32x4 mfma16(bf16x8 a, bf16x8 b, f32x4 c) {
  return __builtin_amdgcn_mfma_f32_16x16x32_bf16(a, b, c, 0, 0, 0);
}

DEV unsigned short f2b(float f) {
  __hip_bfloat16 h = __float2bfloat16(f);
  return __builtin_bit_cast(unsigned short, h);
}

DEV unsigned int cvt_pk_bf16(float lo, float hi) {
  unsigned int r;
  asm("v_cvt_pk_bf16_f32 %0, %1, %2" : "=v"(r) : "v"(lo), "v"(hi));
  return r;
}

// ---------------------------------------------------------------- LayerNorm
__global__ __launch_bounds__(256) void ln_kernel(
    const float* __restrict__ x, const float* __restrict__ gamma,
    const float* __restrict__ beta, __hip_bfloat16* __restrict__ out)
{
  const int row = blockIdx.x, t = threadIdx.x;
  const float4 v = ((const float4*)(x + (size_t)row * 1024))[t];
  float s = v.x + v.y + v.z + v.w;
  float q = v.x * v.x + v.y * v.y + v.z * v.z + v.w * v.w;
#pragma unroll
  for (int m = 1; m < 64; m <<= 1) { s += __shfl_xor(s, m, 64); q += __shfl_xor(q, m, 64); }
  __shared__ float red[8];
  if ((t & 63) == 0) { red[t >> 6] = s; red[4 + (t >> 6)] = q; }
  __syncthreads();
  s = red[0] + red[1] + red[2] + red[3];
  q = red[4] + red[5] + red[6] + red[7];
  const float mu = s * (1.f / 1024.f);
  const float var = q * (1.f / 1024.f) - mu * mu;
  const float rs = rsqrtf(var + 1e-3f);
  const float4 g = ((const float4*)gamma)[t];
  const float4 bt = ((const float4*)beta)[t];
  s16x4 o;
  o[0] = (short)f2b((v.x - mu) * rs * g.x + bt.x);
  o[1] = (short)f2b((v.y - mu) * rs * g.y + bt.y);
  o[2] = (short)f2b((v.z - mu) * rs * g.z + bt.z);
  o[3] = (short)f2b((v.w - mu) * rs * g.w + bt.w);
  *(s16x4*)((short*)out + (size_t)row * 1024 + t * 4) = o;
}

// ------------------------------------------- weight convert + transpose (K=1024)
__global__ __launch_bounds__(256) void wconv(
    const float* __restrict__ W, int N, __hip_bfloat16* __restrict__ Wt)
{
  __shared__ float tile[64][65];
  const int t = threadIdx.x;
  const int k0 = blockIdx.x * 64, n0 = blockIdx.y * 64;
#pragma unroll
  for (int p = 0; p < 4; ++p) {
    int r = p * 16 + (t >> 4), c4 = (t & 15) * 4;
    float4 v = *(const float4*)(W + (size_t)(k0 + r) * N + n0 + c4);
    tile[r][c4] = v.x; tile[r][c4 + 1] = v.y; tile[r][c4 + 2] = v.z; tile[r][c4 + 3] = v.w;
  }
  __syncthreads();
#pragma unroll
  for (int p = 0; p < 4; ++p) {
    int n = p * 16 + (t >> 4), kc = (t & 15) * 4;
    s16x4 o;
    o[0] = (short)f2b(tile[kc][n]);     o[1] = (short)f2b(tile[kc + 1][n]);
    o[2] = (short)f2b(tile[kc + 2][n]); o[3] = (short)f2b(tile[kc + 3][n]);
    *(s16x4*)((short*)Wt + (size_t)(n0 + n) * 1024 + k0 + kc) = o;
  }
}

// ------------------------------------------------------- GEMM: C = A @ Bt^T
template<bool RESID>
__global__ __launch_bounds__(256, 2) void gemm_bt(
    const __hip_bfloat16* __restrict__ A, const __hip_bfloat16* __restrict__ Bt,
    const float* __restrict__ bias0, const float* __restrict__ bias1, int split,
    const __hip_bfloat16* __restrict__ resid,
    __hip_bfloat16* __restrict__ outb, float* __restrict__ outf, int Ncols)
{
  __shared__ __align__(16) short sA[128 * 64];
  __shared__ __align__(16) short sB[128 * 64];
  const int t = threadIdx.x, l = t & 63, w = t >> 6;
  const int wr = w >> 1, wc = w & 1, lr = l & 15, lg = l >> 4;
  const int row0 = blockIdx.y * 128, col0 = blockIdx.x * 128;
  f32x4 acc[4][4] = {};

  for (int kt = 0; kt < 1024; kt += 64) {
#pragma unroll
    for (int p = 0; p < 4; ++p) {
      const int L = p * 4096 + t * 16;
      const int r = L >> 7, c = ((L >> 4) & 7) ^ (r & 7);
      gload_lds16((const char*)A + ((size_t)(row0 + r) * 1024 + kt + c * 8) * 2, (char*)sA + L);
    }
#pragma unroll
    for (int p = 0; p < 4; ++p) {
      const int L = p * 4096 + t * 16;
      const int r = L >> 7, c = ((L >> 4) & 7) ^ (r & 7);
      gload_lds16((const char*)Bt + ((size_t)(col0 + r) * 1024 + kt + c * 8) * 2, (char*)sB + L);
    }
    __syncthreads();

    bf16x8 af[4][2], bfr[4][2];
#pragma unroll
    for (int mb = 0; mb < 4; ++mb) {
      const int ar = wr * 64 + mb * 16 + lr;
#pragma unroll
      for (int kk = 0; kk < 2; ++kk)
        af[mb][kk] = ldsv((const char*)sA + ar * 128 + (((kk * 4 + lg) ^ (ar & 7)) * 16));
    }
#pragma unroll
    for (int nb = 0; nb < 4; ++nb) {
      const int br = wc * 64 + nb * 16 + lr;
#pragma unroll
      for (int kk = 0; kk < 2; ++kk)
        bfr[nb][kk] = ldsv((const char*)sB + br * 128 + (((kk * 4 + lg) ^ (br & 7)) * 16));
    }
#pragma unroll
    for (int kk = 0; kk < 2; ++kk)
#pragma unroll
      for (int mb = 0; mb < 4; ++mb)
#pragma unroll
        for (int nb = 0; nb < 4; ++nb)
          acc[mb][nb] = mfma16(af[mb][kk], bfr[nb][kk], acc[mb][nb]);
    __syncthreads();
  }

#pragma unroll
  for (int mb = 0; mb < 4; ++mb) {
    const int rbase = row0 + wr * 64 + mb * 16 + lg * 4;
#pragma unroll
    for (int nb = 0; nb < 4; ++nb) {
      const int col = col0 + wc * 64 + nb * 16 + lr;
      const float bias = (col < split) ? bias0[col] : bias1[col - split];
#pragma unroll
      for (int jr = 0; jr < 4; ++jr) {
        const size_t idx = (size_t)(rbase + jr) * Ncols + col;
        float v = acc[mb][nb][jr] + bias;
        if (RESID) outf[idx] = v + __bfloat162float(resid[idx]);
        else       outb[idx] = __float2bfloat16(v);
      }
    }
  }
}

// --------------------------------------- V transpose: qkv V-part -> [bh][dv][s]
__global__ __launch_bounds__(256) void vtrans(
    const __hip_bfloat16* __restrict__ qkv, __hip_bfloat16* __restrict__ vt)
{
  __shared__ __align__(16) short tile[64][72];
  const int t = threadIdx.x;
  const int s0 = blockIdx.x * 64;
  const int bh = blockIdx.y, b = bh >> 4, h = bh & 15;
#pragma unroll
  for (int p = 0; p < 2; ++p) {
    int idx = p * 256 + t;
    int r = idx >> 3, c = idx & 7;
    s16x8 vv = *(const s16x8*)((const short*)qkv +
        (size_t)(b * 2048 + s0 + r) * 3072 + 2048 + h * 64 + c * 8);
    *(s16x8*)((char*)tile + r * 144 + c * 16) = vv;
  }
  __syncthreads();
  const int dv = t >> 2, sc = (t & 3) * 16;
  s16x8 a, bvec;
#pragma unroll
  for (int e = 0; e < 8; ++e) a[e] = tile[sc + e][dv];
#pragma unroll
  for (int e = 0; e < 8; ++e) bvec[e] = tile[sc + 8 + e][dv];
  short* dst = (short*)vt + (size_t)(bh * 64 + dv) * 2048 + s0 + sc;
  *(s16x8*)dst = a;
  *(s16x8*)(dst + 8) = bvec;
}

// ----------------------------------------------------------- flash attention
// grid (S/128, B*H); 4 waves x 32 q-rows; KVBLK=64.
// Swapped QK^T: S^T = mfma(K, Q) so each lane's 16 S-values share one q-row
// (q = lr) -> softmax fully in-register. PV B-frag built via cvt_pk + bpermute.
// O^T epilogue bounced through LDS for coalesced stores.
__global__ __launch_bounds__(256, 4) void attn_kernel(
    const __hip_bfloat16* __restrict__ qkv, const __hip_bfloat16* __restrict__ vt,
    const int* __restrict__ lens, __hip_bfloat16* __restrict__ ctx)
{
  __shared__ __align__(16) short sK[2][64 * 64];
  __shared__ __align__(16) short sV[2][64 * 64];
  const int t = threadIdx.x, l = t & 63, w = t >> 6;
  const int lr = l & 15, lg = l >> 4;
  const int bh = blockIdx.y, b = bh >> 4, h = bh & 15;
  const int q0 = blockIdx.x * 128 + w * 32;
  const int len = lens[b];
  const float NEG = -__builtin_inff();
  const float QSC = 0.18033688f;  // 0.125 * log2(e) -> softmax in log2 domain

  // Q fragments (B-operand: lane holds q = lr, d = lg*8+e), scale folded in
  bf16x8 qf[2][2];
#pragma unroll
  for (int mbt = 0; mbt < 2; ++mbt)
#pragma unroll
    for (int kk = 0; kk < 2; ++kk) {
      bf16x8 r = ldsv((const char*)qkv +
          ((size_t)(b * 2048 + q0 + mbt * 16 + lr) * 3072 + h * 64 + kk * 32 + lg * 8) * 2);
#pragma unroll
      for (int e = 0; e < 8; ++e) qf[mbt][kk][e] = (__bf16)((float)r[e] * QSC);
    }

  // o[nbt2][mbt] = O^T tile: lane holds q = lr, dv = nbt2*16 + lg*4 + jr
  f32x4 o[4][2] = {};
  float mrun[2] = {NEG, NEG}, ssum[2] = {0.f, 0.f};

  auto stage = [&](short* dK, short* dV, int kv0) {
#pragma unroll
    for (int p = 0; p < 2; ++p) {
      const int L = p * 4096 + t * 16;
      const int r = L >> 7, c = ((L >> 4) & 7) ^ (r & 7);
      gload_lds16((const char*)qkv +
          ((size_t)(b * 2048 + kv0 + r) * 3072 + 1024 + h * 64 + c * 8) * 2, (char*)dK + L);
    }
#pragma unroll
    for (int p = 0; p < 2; ++p) {
      const int L = p * 4096 + t * 16;
      const int r = L >> 7, c = ((L >> 4) & 7) ^ (r & 7);
      gload_lds16((const char*)vt +
          ((size_t)(bh * 64 + r) * 2048 + kv0 + c * 8) * 2, (char*)dV + L);
    }
  };

  const int nt = (len + 63) >> 6;
  short* curK = sK[0]; short* nxtK = sK[1];
  short* curV = sV[0]; short* nxtV = sV[1];
  stage(curK, curV, 0);

  const int srcA = (lg & 1) * 32 + lr;   // bpermute source lanes for B-frag
  const int srcB = srcA + 16;

  for (int ti = 0; ti < nt; ++ti) {
    const int kv0 = ti * 64;
    if (ti + 1 < nt) {
      stage(nxtK, nxtV, kv0 + 64);
      asm volatile("s_waitcnt vmcnt(4)" ::: "memory");
    } else {
      asm volatile("s_waitcnt vmcnt(0)" ::: "memory");
    }
    __builtin_amdgcn_s_barrier();
    asm volatile("" ::: "memory");

    // ---- S^T = mfma(K, Q): sf[mbt][nbt][jr] at (kv = nbt*16+lg*4+jr, q = mbt*16+lr)
    f32x4 sf[2][4] = {};
    __builtin_amdgcn_s_setprio(1);
#pragma unroll
    for (int kk = 0; kk < 2; ++kk) {
      bf16x8 ak[4];
#pragma unroll
      for (int nbt = 0; nbt < 4; ++nbt) {
        const int br = nbt * 16 + lr;
        ak[nbt] = ldsv((const char*)curK + br * 128 + (((kk * 4 + lg) ^ (br & 7)) * 16));
      }
#pragma unroll
      for (int mbt = 0; mbt < 2; ++mbt)
#pragma unroll
        for (int nbt = 0; nbt < 4; ++nbt)
          sf[mbt][nbt] = mfma16(ak[nbt], qf[mbt][kk], sf[mbt][nbt]);
    }
    __builtin_amdgcn_s_setprio(0);

    // ---- mask tail keys (kv depends on lg now)
    if (kv0 + 64 > len) {
#pragma unroll
      for (int nbt = 0; nbt < 4; ++nbt)
#pragma unroll
        for (int jr = 0; jr < 4; ++jr)
          if (kv0 + nbt * 16 + lg * 4 + jr >= len) {
            sf[0][nbt][jr] = NEG;
            sf[1][nbt][jr] = NEG;
          }
    }

    // ---- in-register online softmax (log2 domain, defer-rescale THR=3)
    float rm[2];
#pragma unroll
    for (int mbt = 0; mbt < 2; ++mbt) {
      f32x4 m4 = sf[mbt][0];
      m4 = __builtin_elementwise_max(m4, sf[mbt][1]);
      m4 = __builtin_elementwise_max(m4, sf[mbt][2]);
      m4 = __builtin_elementwise_max(m4, sf[mbt][3]);
      float m0 = fmaxf(fmaxf(m4[0], m4[1]), fmaxf(m4[2], m4[3]));
      m0 = fmaxf(m0, __shfl_xor(m0, 16, 64));
      m0 = fmaxf(m0, __shfl_xor(m0, 32, 64));
      rm[mbt] = m0;
    }
    const bool need = (rm[0] > mrun[0] + 3.f) || (rm[1] > mrun[1] + 3.f);
    if (__any(need)) {
#pragma unroll
      for (int mbt = 0; mbt < 2; ++mbt) {
        const float mnew = fmaxf(mrun[mbt], rm[mbt]);
        const float corr = __builtin_amdgcn_exp2f(mrun[mbt] - mnew);
        mrun[mbt] = mnew;
        ssum[mbt] *= corr;
#pragma unroll
        for (int nbt2 = 0; nbt2 < 4; ++nbt2) o[nbt2][mbt] *= corr;
      }
    }
    unsigned int W0[2][4], W1[2][4];   // packed bf16 P-pairs per (mbt, nbt)
#pragma unroll
    for (int mbt = 0; mbt < 2; ++mbt) {
      f32x4 ts = {0.f, 0.f, 0.f, 0.f};
#pragma unroll
      for (int nbt = 0; nbt < 4; ++nbt) {
        f32x4 pe;
#pragma unroll
        for (int jr = 0; jr < 4; ++jr)
          pe[jr] = __builtin_amdgcn_exp2f(sf[mbt][nbt][jr] - mrun[mbt]);
        ts += pe;
        W0[mbt][nbt] = cvt_pk_bf16(pe[0], pe[1]);
        W1[mbt][nbt] = cvt_pk_bf16(pe[2], pe[3]);
      }
      ssum[mbt] += (ts[0] + ts[1]) + (ts[2] + ts[3]);
    }

    // ---- PV: O^T += mfma(A=V^T, B=P) ; B-frag assembled via bpermute
#pragma unroll
    for (int c = 0; c < 2; ++c) {
      bf16x8 vf[4], pb[2];
#pragma unroll
      for (int nbt2 = 0; nbt2 < 4; ++nbt2) {
        const int vr = nbt2 * 16 + lr;
        vf[nbt2] = ldsv((const char*)curV + vr * 128 + (((c * 4 + lg) ^ (vr & 7)) * 16));
      }
#pragma unroll
      for (int mbt = 0; mbt < 2; ++mbt) {
        const unsigned int selW0 = (lg & 2) ? W0[mbt][2 * c + 1] : W0[mbt][2 * c];
        const unsigned int selW1 = (lg & 2) ? W1[mbt][2 * c + 1] : W1[mbt][2 * c];
        u32x4 bw;
        bw[0] = __shfl((int)selW0, srcA, 64);
        bw[1] = __shfl((int)selW1, srcA, 64);
        bw[2] = __shfl((int)selW0, srcB, 64);
        bw[3] = __shfl((int)selW1, srcB, 64);
        pb[mbt] = __builtin_bit_cast(bf16x8, bw);
      }
      __builtin_amdgcn_s_setprio(1);
#pragma unroll
      for (int nbt2 = 0; nbt2 < 4; ++nbt2)
#pragma unroll
        for (int mbt = 0; mbt < 2; ++mbt)
          o[nbt2][mbt] = mfma16(vf[nbt2], pb[mbt], o[nbt2][mbt]);
      __builtin_amdgcn_s_setprio(0);
    }

    asm volatile("s_waitcnt lgkmcnt(0)" ::: "memory");
    __builtin_amdgcn_s_barrier();
    asm volatile("" ::: "memory");
    short* tk = curK; curK = nxtK; nxtK = tk;
    short* tv = curV; curV = nxtV; nxtV = tv;
  }

  // ---- epilogue: normalize, transpose O^T -> O via LDS bounce, coalesced store
  float inv[2];
#pragma unroll
  for (int mbt = 0; mbt < 2; ++mbt) {
    float s = ssum[mbt];
    s += __shfl_xor(s, 16, 64);
    s += __shfl_xor(s, 32, 64);
    inv[mbt] = 1.f / s;
  }
  // per-wave private bounce buffer (safe: all waves exited loop past final barrier)
  char* eb = (char*)sK + w * 4352;   // 32 rows x 68 shorts (136 B stride)
#pragma unroll
  for (int mbt = 0; mbt < 2; ++mbt)
#pragma unroll
    for (int nbt2 = 0; nbt2 < 4; ++nbt2)
#pragma unroll
      for (int jr = 0; jr < 4; ++jr)
        *(short*)(eb + (mbt * 16 + lr) * 136 + (nbt2 * 16 + lg * 4 + jr) * 2) =
            (short)f2b(o[nbt2][mbt][jr] * inv[mbt]);
  asm volatile("s_waitcnt lgkmcnt(0)" ::: "memory");
  __builtin_amdgcn_sched_barrier(0);
  const int qi = l >> 1, half = l & 1;
#pragma unroll
  for (int i = 0; i < 4; ++i) {
    s16x8 v = *(const s16x8*)(eb + qi * 136 + half * 64 + i * 16);
    *(s16x8*)((short*)ctx + (size_t)(b * 2048 + q0 + qi) * 1024 + h * 64 + half * 32 + i * 8) = v;
  }
}

// ------------------------------------------------------------------- launch
extern "C" void kernel_launch(void* const* d_in, const int* in_sizes, int n_in,
                              void* d_out, int out_size, void* d_ws, size_t ws_size,
                              hipStream_t stream)
{
  const float* x     = (const float*)d_in[0];
  const int*   lens  = (const int*)d_in[2];
  const float* Wq    = (const float*)d_in[3];
  const float* bq    = (const float*)d_in[4];
  const float* Wkv   = (const float*)d_in[5];
  const float* bkv   = (const float*)d_in[6];
  const float* Wo    = (const float*)d_in[7];
  const float* bo    = (const float*)d_in[8];
  const float* gamma = (const float*)d_in[9];
  const float* beta  = (const float*)d_in[10];
  float* out = (float*)d_out;

  char* ws = (char*)d_ws;
  __hip_bfloat16* ln  = (__hip_bfloat16*)(ws);
  __hip_bfloat16* qkv = (__hip_bfloat16*)(ws + ((size_t)16 << 20));
  __hip_bfloat16* vt  = (__hip_bfloat16*)(ws + ((size_t)64 << 20));
  __hip_bfloat16* ctx = (__hip_bfloat16*)(ws + ((size_t)80 << 20));
  __hip_bfloat16* wt  = (__hip_bfloat16*)(ws + ((size_t)96 << 20));
  __hip_bfloat16* wot = (__hip_bfloat16*)(ws + ((size_t)102 << 20));

  ln_kernel<<<dim3(8192), dim3(256), 0, stream>>>(x, gamma, beta, ln);
  wconv<<<dim3(16, 16), dim3(256), 0, stream>>>(Wq, 1024, wt);
  wconv<<<dim3(16, 32), dim3(256), 0, stream>>>(Wkv, 2048, wt + (size_t)1024 * 1024);
  wconv<<<dim3(16, 16), dim3(256), 0, stream>>>(Wo, 1024, wot);
  gemm_bt<false><<<dim3(24, 64), dim3(256), 0, stream>>>(
      ln, wt, bq, bkv, 1024, (const __hip_bfloat16*)nullptr,
      qkv, (float*)nullptr, 3072);
  vtrans<<<dim3(32, 64), dim3(256), 0, stream>>>(qkv, vt);
  attn_kernel<<<dim3(16, 64), dim3(256), 0, stream>>>(qkv, vt, lens, ctx);
  gemm_bt<true><<<dim3(8, 64), dim3(256), 0, stream>>>(
      ctx, wot, bo, bo, 1 << 30, ln,
      (__hip_bfloat16*)nullptr, out, 1024);
}